// Round 3
// baseline (218.283 us; speedup 1.0000x reference)
//
#include <hip/hip_runtime.h>
#include <math.h>

// Problem constants
#define BDIM 4
#define GDIM 40
#define CDIM 13
#define TDIM 1024
#define FDIM 513                 // T/2 + 1
#define BG   (BDIM*GDIM)         // 160
#define NROW (BG*FDIM)           // 82080 rows of [13] complex
#define NCHUNK 9                 // 9*64 = 576 >= 513 q-rows per bg
#define TK 64                    // K rows per tile

typedef _Float16 half4 __attribute__((ext_vector_type(4)));
typedef _Float16 half8 __attribute__((ext_vector_type(8)));
typedef float    f32x4 __attribute__((ext_vector_type(4)));

#define MFMA16(a, b, c) __builtin_amdgcn_mfma_f32_16x16x16f16((a), (b), (c), 0, 0, 0)
#define MFMA32(a, b, c) __builtin_amdgcn_mfma_f32_16x16x32_f16((a), (b), (c), 0, 0, 0)

__device__ __forceinline__ unsigned bitrev10(unsigned x) { return __brev(x) >> 22; }

// ---------------- Kernel 1: two-for-one rfft(1024) ----------------
__global__ void fft_fwd2(const float* __restrict__ x, float2* __restrict__ xf) {
    __shared__ float re[1024], im[1024];
    const int s2 = blockIdx.x;                   // pair index, 0..1039
    const float* x1 = x + (size_t)(2 * s2) * TDIM;
    const float* x2 = x1 + TDIM;
    for (int t = threadIdx.x; t < 1024; t += blockDim.x) {
        unsigned r = bitrev10(t);
        re[r] = x1[t];
        im[r] = x2[t];
    }
    __syncthreads();
    for (int s = 0; s < 10; ++s) {
        int half = 1 << s;
        for (int j = threadIdx.x; j < 512; j += blockDim.x) {
            int grp = j >> s;
            int pos = j & (half - 1);
            int i1 = (grp << (s + 1)) + pos;
            int i2 = i1 + half;
            float ang = -(float)M_PI * (float)pos / (float)half;
            float sw, cw; __sincosf(ang, &sw, &cw);
            float xr = re[i2], xi = im[i2];
            float tr = cw * xr - sw * xi;
            float ti = cw * xi + sw * xr;
            float ur = re[i1], ui = im[i1];
            re[i1] = ur + tr; im[i1] = ui + ti;
            re[i2] = ur - tr; im[i2] = ui - ti;
        }
        __syncthreads();
    }
    const int sigA = 2 * s2, sigB = sigA + 1;
    const int bgA = sigA / CDIM, cA = sigA % CDIM;
    const int bgB = sigB / CDIM, cB = sigB % CDIM;
    for (int f = threadIdx.x; f < FDIM; f += blockDim.x) {
        int fr = (1024 - f) & 1023;
        float zr = re[f], zi = im[f];
        float wr = re[fr], wi = im[fr];
        xf[((size_t)bgA * FDIM + f) * CDIM + cA] =
            make_float2(0.5f * (zr + wr), 0.5f * (zi - wi));
        xf[((size_t)bgB * FDIM + f) * CDIM + cB] =
            make_float2(0.5f * (zi + wi), 0.5f * (wr - zr));
    }
}

// ---------------- Kernel 2: Q/K/V projections ----------------
// q: float2 rows (for in-reg Q-fragment build in attn).
// KP: per row 64 halves [hi(kr)0..12 | hi(ki)@13..25 | 0 @26..31 | lo(kr)@32..44 | lo(ki)@45..57 | 0 @58..63]
// VT: fp16, transposed: [bg][re/im][c(16)][f stride 520]
__global__ void qkv_kernel(const float2* __restrict__ xf,
                           const float* __restrict__ wq,
                           const float* __restrict__ wk,
                           const float* __restrict__ wv,
                           float2* __restrict__ q,
                           _Float16* __restrict__ KP,
                           _Float16* __restrict__ VT) {
    int gid = blockIdx.x * blockDim.x + threadIdx.x;
    if (gid >= NROW * CDIM) return;
    int r = gid / CDIM;
    int i = gid - r * CDIM;
    const float2* xrow = xf + (size_t)r * CDIM;
    float qr = 0, qi = 0, kr = 0, ki = 0, vr = 0, vi = 0;
#pragma unroll
    for (int c = 0; c < CDIM; ++c) {
        float2 xc = xrow[c];
        float a = wq[c * CDIM + i]; qr += xc.x * a; qi += xc.y * a;
        float b = wk[c * CDIM + i]; kr += xc.x * b; ki += xc.y * b;
        float d = wv[c * CDIM + i]; vr += xc.x * d; vi += xc.y * d;
    }
    q[gid] = make_float2(qr, qi);

    _Float16* krow = KP + (size_t)r * 64;
    _Float16 h0 = (_Float16)kr;
    _Float16 h1 = (_Float16)ki;
    krow[i]      = h0;
    krow[13 + i] = h1;
    krow[32 + i] = (_Float16)(kr - (float)h0);
    krow[45 + i] = (_Float16)(ki - (float)h1);
    if (i == 12) {   // zero the pad halves 26..31 and 58..63
        *(unsigned int*)(krow + 26) = 0u;
        *(unsigned int*)(krow + 28) = 0u;
        *(unsigned int*)(krow + 30) = 0u;
        *(unsigned int*)(krow + 58) = 0u;
        *(unsigned int*)(krow + 60) = 0u;
        *(unsigned int*)(krow + 62) = 0u;
    }
    int bg = r / FDIM;
    int f  = r - bg * FDIM;
    VT[((size_t)(bg * 2 + 0) * 16 + i) * 520 + f] = (_Float16)vr;
    VT[((size_t)(bg * 2 + 1) * 16 + i) * 520 + f] = (_Float16)vi;
}

// ---------------- Kernel 3: MFMA flash attention (k-split, 2 q-sets/wave) ----------------
// Block = 4 waves: wave w = (qpair = w&1, kh = w>>1).
// Wave owns 32 q-rows (2 MFMA q-sets) and K-tiles of parity kh (double-buffered pairs).
// Scores: mfma_f32_16x16x32_f16, A = K-rows (hi/lo fp16 from LDS), B = Q (hi/lo, regs).
//   x32 fragment = concat of two x16 k-chunk fragments: elem e=4c+j <-> k=16c+4g+j.
//   Re = u.w with u=[qr,-qi], Im = u'.w with u'=[qi,qr]  (plain complex product q.k).
// Score D layout: q = lane&15, kidx = 4*(lane>>4)+reg == PV B-fragment layout.
// PV: A = V^T tile (fp16) (rows = channel), B = P. Online softmax with deferred rescale.
// End: kh=1 partials merged into kh=0 via LDS (reusing K buffer).
__global__ __launch_bounds__(256, 5) void attn_kernel(const float2* __restrict__ q,
                                                      const _Float16* __restrict__ KP,
                                                      const _Float16* __restrict__ VT,
                                                      float2* __restrict__ outspec) {
    __shared__ __align__(16) _Float16 Klds[2 * TK * 64];     // 16 KB: 2 tile buffers (parity)
    __shared__ __align__(16) _Float16 VTlds[2 * 2 * 16 * 72]; // 9.2 KB

    const int bg    = blockIdx.x / NCHUNK;
    const int chunk = blockIdx.x % NCHUNK;
    const int tid   = threadIdx.x;
    const int w     = tid >> 6;
    const int lane  = tid & 63;
    const int qlane = lane & 15;
    const int g     = lane >> 4;
    const int qpair = w & 1;
    const int kh    = w >> 1;

    // ---- build Q fragments for the wave's two q-sets ----
    half8 Quh[2], Qul[2], Qu2h[2], Qu2l[2];
    int   frow_s[2];
#pragma unroll
    for (int s = 0; s < 2; ++s) {
        frow_s[s] = chunk * 64 + (qpair * 2 + s) * 16 + qlane;
        const int f = (frow_s[s] < FDIM) ? frow_s[s] : (FDIM - 1);
        const size_t rowbase = ((size_t)bg * FDIM + f) * CDIM;
#pragma unroll
        for (int c = 0; c < 2; ++c) {
#pragma unroll
            for (int j = 0; j < 4; ++j) {
                const int e = 4 * c + j;
                const int k = 16 * c + 4 * g + j;
                float a = 0.f, b = 0.f;
                if (k < CDIM) {
                    float2 t = q[rowbase + k];          a = t.x;  b = t.y;
                } else if (k < 2 * CDIM) {
                    float2 t = q[rowbase + (k - CDIM)]; a = -t.y; b = t.x;
                }
                _Float16 ah = (_Float16)a;
                Quh[s][e]  = ah;
                Qul[s][e]  = (_Float16)(a - (float)ah);
                _Float16 bh = (_Float16)b;
                Qu2h[s][e] = bh;
                Qu2l[s][e] = (_Float16)(b - (float)bh);
            }
        }
    }

    f32x4 ore[2], oim[2];
    float m[2], l[2];
#pragma unroll
    for (int s = 0; s < 2; ++s) {
        ore[s] = (f32x4){0.f, 0.f, 0.f, 0.f};
        oim[s] = (f32x4){0.f, 0.f, 0.f, 0.f};
        m[s] = -INFINITY; l[s] = 0.f;
    }

    const _Float16* __restrict__ KPg = KP + (size_t)bg * FDIM * 64;
    const _Float16* __restrict__ VTg = VT + (size_t)bg * 2 * 16 * 520;
    const _Float16* KB = Klds  + kh * (TK * 64);
    const _Float16* VB = VTlds + kh * (2 * 16 * 72);

    for (int it = 0; it < 5; ++it) {                 // tile pairs (2it, 2it+1)
        __syncthreads();                             // previous pair fully consumed
        // ---- stage K: 4 granules of 16B per thread over the 2 tiles ----
#pragma unroll
        for (int h = 0; h < 4; ++h) {
            int gidx = tid + h * 256;                // 0..1023
            int b  = gidx >> 9;
            int g2 = gidx & 511;
            int t  = 2 * it + b;
            if (t <= 8) {
                int krw = g2 >> 3, gg = g2 & 7;
                half8 val;
#pragma unroll
                for (int e = 0; e < 8; ++e) val[e] = (_Float16)0.f;
                int grow = t * TK + krw;
                if (grow < FDIM)
                    val = *(const half8*)(KPg + (size_t)grow * 64 + gg * 8);
                *(half8*)(Klds + b * (TK * 64) + krw * 64 + ((gg ^ (krw & 7)) << 3)) = val;
            }
        }
        // ---- stage V^T: 2 granules per thread over the 2 tiles ----
#pragma unroll
        for (int h = 0; h < 2; ++h) {
            int gidx = tid + h * 256;                // 0..511
            int b  = gidx >> 8;
            int g2 = gidx & 255;
            int t  = 2 * it + b;
            if (t <= 8) {
                int part = g2 >> 7, cc = (g2 >> 3) & 15, gk = g2 & 7;
                int rb = t * TK + gk * 8;
                half8 val;
#pragma unroll
                for (int e = 0; e < 8; ++e) val[e] = (_Float16)0.f;
                if (rb < FDIM) {
                    val = *(const half8*)(VTg + ((size_t)(part * 16 + cc)) * 520 + rb);
                    if (rb + 8 > FDIM) {
#pragma unroll
                        for (int e = 0; e < 8; ++e) if (rb + e >= FDIM) val[e] = (_Float16)0.f;
                    }
                }
                *(half8*)(VTlds + b * (2 * 16 * 72) + (part * 16 + cc) * 72 + gk * 8) = val;
            }
        }
        __syncthreads();

        const int t = 2 * it + kh;
        if (t <= 8) {                                // wave-uniform (only it=4,kh=1 skips)
            // ---- 4 sub-tiles of 16 keys ----
#pragma unroll
            for (int sub = 0; sub < 4; ++sub) {
                const int arow = sub * 16 + qlane;
                const int rx   = arow & 7;
                const _Float16* kr = KB + arow * 64;
#define KFRAG(h) (*(const half4*)(kr + ((((h) >> 3) ^ rx) << 3) + ((h) & 7)))
                half4 a0 = KFRAG(4 * g);
                half4 a1 = KFRAG(16 + 4 * g);
                half4 a2 = KFRAG(32 + 4 * g);
                half4 a3 = KFRAG(48 + 4 * g);
#undef KFRAG
                half8 whh, wll;
#pragma unroll
                for (int j = 0; j < 4; ++j) {
                    whh[j] = a0[j]; whh[4 + j] = a1[j];
                    wll[j] = a2[j]; wll[4 + j] = a3[j];
                }

                float sv[2][4], tmax[2];
#pragma unroll
                for (int s = 0; s < 2; ++s) {
                    f32x4 sre = {0.f, 0.f, 0.f, 0.f};
                    f32x4 sim = {0.f, 0.f, 0.f, 0.f};
                    sre = MFMA32(whh, Quh[s], sre);
                    sre = MFMA32(wll, Quh[s], sre);
                    sre = MFMA32(whh, Qul[s], sre);
                    sre = MFMA32(wll, Qul[s], sre);
                    sim = MFMA32(whh, Qu2h[s], sim);
                    sim = MFMA32(wll, Qu2h[s], sim);
                    sim = MFMA32(whh, Qu2l[s], sim);
                    sim = MFMA32(wll, Qu2l[s], sim);
                    sv[s][0] = sqrtf(fmaf(sre[0], sre[0], sim[0] * sim[0]));
                    sv[s][1] = sqrtf(fmaf(sre[1], sre[1], sim[1] * sim[1]));
                    sv[s][2] = sqrtf(fmaf(sre[2], sre[2], sim[2] * sim[2]));
                    sv[s][3] = sqrtf(fmaf(sre[3], sre[3], sim[3] * sim[3]));
                    float tm = fmaxf(fmaxf(sv[s][0], sv[s][1]), fmaxf(sv[s][2], sv[s][3]));
                    tm = fmaxf(tm, __shfl_xor(tm, 16));
                    tm = fmaxf(tm, __shfl_xor(tm, 32));
                    tmax[s] = tm;
                }
                // deferred rescale (T13): skip while max grows by <= 8
                if (!__all((tmax[0] <= m[0] + 8.f) & (tmax[1] <= m[1] + 8.f))) {
#pragma unroll
                    for (int s = 0; s < 2; ++s) {
                        float mnew  = fmaxf(m[s], tmax[s]);
                        float alpha = __expf(m[s] - mnew);   // exp(-inf)=0 first time
                        l[s]  *= alpha;
                        ore[s] *= alpha;
                        oim[s] *= alpha;
                        m[s] = mnew;
                    }
                }
                const int voff = sub * 16 + 4 * g;
                half4 vfr = *(const half4*)(VB + qlane * 72 + voff);
                half4 vfi = *(const half4*)(VB + (16 + qlane) * 72 + voff);
#pragma unroll
                for (int s = 0; s < 2; ++s) {
                    float p0 = __expf(sv[s][0] - m[s]);
                    float p1 = __expf(sv[s][1] - m[s]);
                    float p2 = __expf(sv[s][2] - m[s]);
                    float p3 = __expf(sv[s][3] - m[s]);
                    l[s] += (p0 + p1) + (p2 + p3);
                    half4 pk;
                    pk[0] = (_Float16)p0; pk[1] = (_Float16)p1;
                    pk[2] = (_Float16)p2; pk[3] = (_Float16)p3;
                    ore[s] = MFMA16(vfr, pk, ore[s]);
                    oim[s] = MFMA16(vfi, pk, oim[s]);
                }
            }
        }
    }

    // ---- merge kh=1 partials into kh=0 (reuse Klds as float buffer) ----
    __syncthreads();                                 // all compute done
    float* MB = (float*)Klds;                        // 128 slots x 20 floats = 10.2 KB
    if (kh == 1) {
        float* dst = MB + (qpair * 64 + lane) * 20;
#pragma unroll
        for (int s = 0; s < 2; ++s) {
            dst[10 * s + 0] = m[s];
            dst[10 * s + 1] = l[s];
#pragma unroll
            for (int j = 0; j < 4; ++j) {
                dst[10 * s + 2 + j] = ore[s][j];
                dst[10 * s + 6 + j] = oim[s][j];
            }
        }
    }
    __syncthreads();
    if (kh == 0) {
        const float* src = MB + (qpair * 64 + lane) * 20;
#pragma unroll
        for (int s = 0; s < 2; ++s) {
            float mp = src[10 * s + 0], lp = src[10 * s + 1];
            float M  = fmaxf(m[s], mp);
            float sa = __expf(m[s] - M), sb = __expf(mp - M);
            l[s] = l[s] * sa + lp * sb;
#pragma unroll
            for (int j = 0; j < 4; ++j) {
                ore[s][j] = ore[s][j] * sa + src[10 * s + 2 + j] * sb;
                oim[s][j] = oim[s][j] * sa + src[10 * s + 6 + j] * sb;
            }
            // total l per q-row: sum the 4 g-group partials
            float lt = l[s];
            lt += __shfl_xor(lt, 16);
            lt += __shfl_xor(lt, 32);
            if (frow_s[s] < FDIM) {
                float inv = 1.f / lt;
#pragma unroll
                for (int j = 0; j < 4; ++j) {
                    int c = 4 * g + j;
                    if (c < CDIM)
                        outspec[((size_t)(bg * CDIM + c)) * FDIM + frow_s[s]] =
                            make_float2(ore[s][j] * inv, oim[s][j] * inv);
                }
            }
        }
    }
}

// ---------------- Kernel 4: two-for-one irfft(1024) ----------------
__global__ void fft_inv2(const float2* __restrict__ spec, float* __restrict__ out) {
    __shared__ float re[1024], im[1024];
    const int s2 = blockIdx.x;                   // pair 0..1039
    const float2* Y1 = spec + (size_t)(2 * s2) * FDIM;
    const float2* Y2 = Y1 + FDIM;
    for (int t = threadIdx.x; t < 1024; t += blockDim.x) {
        float a, b, c, d;
        if (t <= 512) {
            float2 y1 = Y1[t], y2 = Y2[t];
            bool edge = (t == 0) | (t == 512);
            a = y1.x; b = edge ? 0.f : y1.y;
            c = y2.x; d = edge ? 0.f : y2.y;
        } else {
            float2 y1 = Y1[1024 - t], y2 = Y2[1024 - t];
            a = y1.x; b = -y1.y;
            c = y2.x; d = -y2.y;
        }
        unsigned r = bitrev10(t);
        re[r] = a - d;
        im[r] = b + c;
    }
    __syncthreads();
    for (int s = 0; s < 10; ++s) {
        int half = 1 << s;
        for (int j = threadIdx.x; j < 512; j += blockDim.x) {
            int grp = j >> s;
            int pos = j & (half - 1);
            int i1 = (grp << (s + 1)) + pos;
            int i2 = i1 + half;
            float ang = (float)M_PI * (float)pos / (float)half;   // +sign = inverse
            float sw, cw; __sincosf(ang, &sw, &cw);
            float xr = re[i2], xi = im[i2];
            float tr = cw * xr - sw * xi;
            float ti = cw * xi + sw * xr;
            float ur = re[i1], ui = im[i1];
            re[i1] = ur + tr; im[i1] = ui + ti;
            re[i2] = ur - tr; im[i2] = ui - ti;
        }
        __syncthreads();
    }
    const float scale = 1.0f / 1024.0f;
    float* o1 = out + (size_t)(2 * s2) * TDIM;
    for (int t = threadIdx.x; t < 1024; t += blockDim.x) {
        o1[t]        = re[t] * scale;
        o1[TDIM + t] = im[t] * scale;
    }
}

extern "C" void kernel_launch(void* const* d_in, const int* in_sizes, int n_in,
                              void* d_out, int out_size, void* d_ws, size_t ws_size,
                              hipStream_t stream) {
    const float* x  = (const float*)d_in[0];
    const float* wq = (const float*)d_in[1];
    const float* wk = (const float*)d_in[2];
    const float* wv = (const float*)d_in[3];
    float* out = (float*)d_out;

    const size_t n = (size_t)NROW * CDIM;        // 1,067,040 complex per buffer
    float2* xf = (float2*)d_ws;                  // x_fft, later reused as out-spectrum
    float2* q  = xf + n;                         // 8.54 MB
    _Float16* KP = (_Float16*)(q + n);           // NROW*64 halves = 10.51 MB
    _Float16* VT = KP + (size_t)NROW * 64;       // BG*2*16*520 halves = 5.32 MB

    fft_fwd2<<<BG * CDIM / 2, 256, 0, stream>>>(x, xf);
    qkv_kernel<<<(NROW * CDIM + 255) / 256, 256, 0, stream>>>(xf, wq, wk, wv, q, KP, VT);
    attn_kernel<<<BG * NCHUNK, 256, 0, stream>>>(q, KP, VT, xf /* outspec, aliases xf */);
    fft_inv2<<<BG * CDIM / 2, 256, 0, stream>>>(xf, out);
}

// Round 4
// 196.140 us; speedup vs baseline: 1.1129x; 1.1129x over previous
//
#include <hip/hip_runtime.h>
#include <math.h>

// Problem constants
#define BDIM 4
#define GDIM 40
#define CDIM 13
#define TDIM 1024
#define FDIM 513                 // T/2 + 1
#define BG   (BDIM*GDIM)         // 160
#define NROW (BG*FDIM)           // 82080 rows of [13] complex
#define NCHUNK 9                 // 9*64 = 576 >= 513 q-rows per bg
#define TK 64                    // K rows per tile

typedef _Float16 half4 __attribute__((ext_vector_type(4)));
typedef _Float16 half8 __attribute__((ext_vector_type(8)));
typedef float    f32x4 __attribute__((ext_vector_type(4)));

#define MFMA16(a, b, c) __builtin_amdgcn_mfma_f32_16x16x16f16((a), (b), (c), 0, 0, 0)
#define MFMA32(a, b, c) __builtin_amdgcn_mfma_f32_16x16x32_f16((a), (b), (c), 0, 0, 0)

__device__ __forceinline__ unsigned bitrev10(unsigned x) { return __brev(x) >> 22; }

// ---------------- Kernel 1: two-for-one rfft(1024) ----------------
__global__ void fft_fwd2(const float* __restrict__ x, float2* __restrict__ xf) {
    __shared__ float re[1024], im[1024];
    const int s2 = blockIdx.x;                   // pair index, 0..1039
    const float* x1 = x + (size_t)(2 * s2) * TDIM;
    const float* x2 = x1 + TDIM;
    for (int t = threadIdx.x; t < 1024; t += blockDim.x) {
        unsigned r = bitrev10(t);
        re[r] = x1[t];
        im[r] = x2[t];
    }
    __syncthreads();
    for (int s = 0; s < 10; ++s) {
        int half = 1 << s;
        for (int j = threadIdx.x; j < 512; j += blockDim.x) {
            int grp = j >> s;
            int pos = j & (half - 1);
            int i1 = (grp << (s + 1)) + pos;
            int i2 = i1 + half;
            float ang = -(float)M_PI * (float)pos / (float)half;
            float sw, cw; __sincosf(ang, &sw, &cw);
            float xr = re[i2], xi = im[i2];
            float tr = cw * xr - sw * xi;
            float ti = cw * xi + sw * xr;
            float ur = re[i1], ui = im[i1];
            re[i1] = ur + tr; im[i1] = ui + ti;
            re[i2] = ur - tr; im[i2] = ui - ti;
        }
        __syncthreads();
    }
    const int sigA = 2 * s2, sigB = sigA + 1;
    const int bgA = sigA / CDIM, cA = sigA % CDIM;
    const int bgB = sigB / CDIM, cB = sigB % CDIM;
    for (int f = threadIdx.x; f < FDIM; f += blockDim.x) {
        int fr = (1024 - f) & 1023;
        float zr = re[f], zi = im[f];
        float wr = re[fr], wi = im[fr];
        xf[((size_t)bgA * FDIM + f) * CDIM + cA] =
            make_float2(0.5f * (zr + wr), 0.5f * (zi - wi));
        xf[((size_t)bgB * FDIM + f) * CDIM + cB] =
            make_float2(0.5f * (zi + wi), 0.5f * (wr - zr));
    }
}

// ---------------- Kernel 2: Q/K/V projections ----------------
// q: float2 rows (for in-reg Q-fragment build in attn).
// KP: per row 64 halves [hi(kr)0..12 | hi(ki)@13..25 | 0 @26..31 | lo(kr)@32..44 | lo(ki)@45..57 | 0 @58..63]
// VT: fp16, transposed: [bg][re/im][c(16)][f stride 520]
__global__ void qkv_kernel(const float2* __restrict__ xf,
                           const float* __restrict__ wq,
                           const float* __restrict__ wk,
                           const float* __restrict__ wv,
                           float2* __restrict__ q,
                           _Float16* __restrict__ KP,
                           _Float16* __restrict__ VT) {
    int gid = blockIdx.x * blockDim.x + threadIdx.x;
    if (gid >= NROW * CDIM) return;
    int r = gid / CDIM;
    int i = gid - r * CDIM;
    const float2* xrow = xf + (size_t)r * CDIM;
    float qr = 0, qi = 0, kr = 0, ki = 0, vr = 0, vi = 0;
#pragma unroll
    for (int c = 0; c < CDIM; ++c) {
        float2 xc = xrow[c];
        float a = wq[c * CDIM + i]; qr += xc.x * a; qi += xc.y * a;
        float b = wk[c * CDIM + i]; kr += xc.x * b; ki += xc.y * b;
        float d = wv[c * CDIM + i]; vr += xc.x * d; vi += xc.y * d;
    }
    q[gid] = make_float2(qr, qi);

    _Float16* krow = KP + (size_t)r * 64;
    _Float16 h0 = (_Float16)kr;
    _Float16 h1 = (_Float16)ki;
    krow[i]      = h0;
    krow[13 + i] = h1;
    krow[32 + i] = (_Float16)(kr - (float)h0);
    krow[45 + i] = (_Float16)(ki - (float)h1);
    if (i == 12) {   // zero the pad halves 26..31 and 58..63
        *(unsigned int*)(krow + 26) = 0u;
        *(unsigned int*)(krow + 28) = 0u;
        *(unsigned int*)(krow + 30) = 0u;
        *(unsigned int*)(krow + 58) = 0u;
        *(unsigned int*)(krow + 60) = 0u;
        *(unsigned int*)(krow + 62) = 0u;
    }
    int bg = r / FDIM;
    int f  = r - bg * FDIM;
    VT[((size_t)(bg * 2 + 0) * 16 + i) * 520 + f] = (_Float16)vr;
    VT[((size_t)(bg * 2 + 1) * 16 + i) * 520 + f] = (_Float16)vi;
}

// ---------------- Kernel 3: MFMA flash attention (k-split, 2 q-sets/wave) ----------------
// Block = 4 waves: wave w = (qpair = w&1, kh = w>>1).
// Wave owns 32 q-rows (2 MFMA q-sets) and K-tiles of parity kh (double-buffered pairs).
// Scores: mfma_f32_16x16x32_f16, A = K-rows (hi/lo fp16 from LDS), B = Q (hi/lo, regs).
//   x32 fragment = concat of two x16 k-chunk fragments: elem e=4c+j <-> k=16c+4g+j.
//   Re = u.w with u=[qr,-qi], Im = u'.w with u'=[qi,qr]  (plain complex product q.k).
// Score D layout: q = lane&15, kidx = 4*(lane>>4)+reg == PV B-fragment layout.
// PV: A = V^T tile (fp16) (rows = channel), B = P. Online softmax with deferred rescale.
// End: kh=1 partials merged into kh=0 via LDS (reusing K buffer).
// launch_bounds(256,3): VGPR budget ~170 for ~110-120 live regs. (256,5) in the
// previous round squeezed the allocator to 48 VGPRs -> scratch spill (43 MB
// WRITE_SIZE, +53 MB FETCH_SIZE) -> 105 us. Do NOT tighten without re-counting.
__global__ __launch_bounds__(256, 3) void attn_kernel(const float2* __restrict__ q,
                                                      const _Float16* __restrict__ KP,
                                                      const _Float16* __restrict__ VT,
                                                      float2* __restrict__ outspec) {
    __shared__ __align__(16) _Float16 Klds[2 * TK * 64];     // 16 KB: 2 tile buffers (parity)
    __shared__ __align__(16) _Float16 VTlds[2 * 2 * 16 * 72]; // 9.2 KB

    const int bg    = blockIdx.x / NCHUNK;
    const int chunk = blockIdx.x % NCHUNK;
    const int tid   = threadIdx.x;
    const int w     = tid >> 6;
    const int lane  = tid & 63;
    const int qlane = lane & 15;
    const int g     = lane >> 4;
    const int qpair = w & 1;
    const int kh    = w >> 1;

    // ---- build Q fragments for the wave's two q-sets ----
    half8 Quh[2], Qul[2], Qu2h[2], Qu2l[2];
    int   frow_s[2];
#pragma unroll
    for (int s = 0; s < 2; ++s) {
        frow_s[s] = chunk * 64 + (qpair * 2 + s) * 16 + qlane;
        const int f = (frow_s[s] < FDIM) ? frow_s[s] : (FDIM - 1);
        const size_t rowbase = ((size_t)bg * FDIM + f) * CDIM;
#pragma unroll
        for (int c = 0; c < 2; ++c) {
#pragma unroll
            for (int j = 0; j < 4; ++j) {
                const int e = 4 * c + j;
                const int k = 16 * c + 4 * g + j;
                float a = 0.f, b = 0.f;
                if (k < CDIM) {
                    float2 t = q[rowbase + k];          a = t.x;  b = t.y;
                } else if (k < 2 * CDIM) {
                    float2 t = q[rowbase + (k - CDIM)]; a = -t.y; b = t.x;
                }
                _Float16 ah = (_Float16)a;
                Quh[s][e]  = ah;
                Qul[s][e]  = (_Float16)(a - (float)ah);
                _Float16 bh = (_Float16)b;
                Qu2h[s][e] = bh;
                Qu2l[s][e] = (_Float16)(b - (float)bh);
            }
        }
    }

    f32x4 ore[2], oim[2];
    float m[2], l[2];
#pragma unroll
    for (int s = 0; s < 2; ++s) {
        ore[s] = (f32x4){0.f, 0.f, 0.f, 0.f};
        oim[s] = (f32x4){0.f, 0.f, 0.f, 0.f};
        m[s] = -INFINITY; l[s] = 0.f;
    }

    const _Float16* __restrict__ KPg = KP + (size_t)bg * FDIM * 64;
    const _Float16* __restrict__ VTg = VT + (size_t)bg * 2 * 16 * 520;
    const _Float16* KB = Klds  + kh * (TK * 64);
    const _Float16* VB = VTlds + kh * (2 * 16 * 72);

    for (int it = 0; it < 5; ++it) {                 // tile pairs (2it, 2it+1)
        __syncthreads();                             // previous pair fully consumed
        // ---- stage K: 4 granules of 16B per thread over the 2 tiles ----
#pragma unroll
        for (int h = 0; h < 4; ++h) {
            int gidx = tid + h * 256;                // 0..1023
            int b  = gidx >> 9;
            int g2 = gidx & 511;
            int t  = 2 * it + b;
            if (t <= 8) {
                int krw = g2 >> 3, gg = g2 & 7;
                half8 val;
#pragma unroll
                for (int e = 0; e < 8; ++e) val[e] = (_Float16)0.f;
                int grow = t * TK + krw;
                if (grow < FDIM)
                    val = *(const half8*)(KPg + (size_t)grow * 64 + gg * 8);
                *(half8*)(Klds + b * (TK * 64) + krw * 64 + ((gg ^ (krw & 7)) << 3)) = val;
            }
        }
        // ---- stage V^T: 2 granules per thread over the 2 tiles ----
#pragma unroll
        for (int h = 0; h < 2; ++h) {
            int gidx = tid + h * 256;                // 0..511
            int b  = gidx >> 8;
            int g2 = gidx & 255;
            int t  = 2 * it + b;
            if (t <= 8) {
                int part = g2 >> 7, cc = (g2 >> 3) & 15, gk = g2 & 7;
                int rb = t * TK + gk * 8;
                half8 val;
#pragma unroll
                for (int e = 0; e < 8; ++e) val[e] = (_Float16)0.f;
                if (rb < FDIM) {
                    val = *(const half8*)(VTg + ((size_t)(part * 16 + cc)) * 520 + rb);
                    if (rb + 8 > FDIM) {
#pragma unroll
                        for (int e = 0; e < 8; ++e) if (rb + e >= FDIM) val[e] = (_Float16)0.f;
                    }
                }
                *(half8*)(VTlds + b * (2 * 16 * 72) + (part * 16 + cc) * 72 + gk * 8) = val;
            }
        }
        __syncthreads();

        const int t = 2 * it + kh;
        if (t <= 8) {                                // wave-uniform (only it=4,kh=1 skips)
            // ---- 4 sub-tiles of 16 keys ----
#pragma unroll
            for (int sub = 0; sub < 4; ++sub) {
                const int arow = sub * 16 + qlane;
                const int rx   = arow & 7;
                const _Float16* kr = KB + arow * 64;
#define KFRAG(h) (*(const half4*)(kr + ((((h) >> 3) ^ rx) << 3) + ((h) & 7)))
                half4 a0 = KFRAG(4 * g);
                half4 a1 = KFRAG(16 + 4 * g);
                half4 a2 = KFRAG(32 + 4 * g);
                half4 a3 = KFRAG(48 + 4 * g);
#undef KFRAG
                half8 whh, wll;
#pragma unroll
                for (int j = 0; j < 4; ++j) {
                    whh[j] = a0[j]; whh[4 + j] = a1[j];
                    wll[j] = a2[j]; wll[4 + j] = a3[j];
                }

                float sv[2][4], tmax[2];
#pragma unroll
                for (int s = 0; s < 2; ++s) {
                    f32x4 sre = {0.f, 0.f, 0.f, 0.f};
                    f32x4 sim = {0.f, 0.f, 0.f, 0.f};
                    sre = MFMA32(whh, Quh[s], sre);
                    sre = MFMA32(wll, Quh[s], sre);
                    sre = MFMA32(whh, Qul[s], sre);
                    sre = MFMA32(wll, Qul[s], sre);
                    sim = MFMA32(whh, Qu2h[s], sim);
                    sim = MFMA32(wll, Qu2h[s], sim);
                    sim = MFMA32(whh, Qu2l[s], sim);
                    sim = MFMA32(wll, Qu2l[s], sim);
                    sv[s][0] = sqrtf(fmaf(sre[0], sre[0], sim[0] * sim[0]));
                    sv[s][1] = sqrtf(fmaf(sre[1], sre[1], sim[1] * sim[1]));
                    sv[s][2] = sqrtf(fmaf(sre[2], sre[2], sim[2] * sim[2]));
                    sv[s][3] = sqrtf(fmaf(sre[3], sre[3], sim[3] * sim[3]));
                    float tm = fmaxf(fmaxf(sv[s][0], sv[s][1]), fmaxf(sv[s][2], sv[s][3]));
                    tm = fmaxf(tm, __shfl_xor(tm, 16));
                    tm = fmaxf(tm, __shfl_xor(tm, 32));
                    tmax[s] = tm;
                }
                // deferred rescale (T13): skip while max grows by <= 8
                if (!__all((tmax[0] <= m[0] + 8.f) & (tmax[1] <= m[1] + 8.f))) {
#pragma unroll
                    for (int s = 0; s < 2; ++s) {
                        float mnew  = fmaxf(m[s], tmax[s]);
                        float alpha = __expf(m[s] - mnew);   // exp(-inf)=0 first time
                        l[s]  *= alpha;
                        ore[s] *= alpha;
                        oim[s] *= alpha;
                        m[s] = mnew;
                    }
                }
                const int voff = sub * 16 + 4 * g;
                half4 vfr = *(const half4*)(VB + qlane * 72 + voff);
                half4 vfi = *(const half4*)(VB + (16 + qlane) * 72 + voff);
#pragma unroll
                for (int s = 0; s < 2; ++s) {
                    float p0 = __expf(sv[s][0] - m[s]);
                    float p1 = __expf(sv[s][1] - m[s]);
                    float p2 = __expf(sv[s][2] - m[s]);
                    float p3 = __expf(sv[s][3] - m[s]);
                    l[s] += (p0 + p1) + (p2 + p3);
                    half4 pk;
                    pk[0] = (_Float16)p0; pk[1] = (_Float16)p1;
                    pk[2] = (_Float16)p2; pk[3] = (_Float16)p3;
                    ore[s] = MFMA16(vfr, pk, ore[s]);
                    oim[s] = MFMA16(vfi, pk, oim[s]);
                }
            }
        }
    }

    // ---- merge kh=1 partials into kh=0 (reuse Klds as float buffer) ----
    __syncthreads();                                 // all compute done
    float* MB = (float*)Klds;                        // 128 slots x 20 floats = 10.2 KB
    if (kh == 1) {
        float* dst = MB + (qpair * 64 + lane) * 20;
#pragma unroll
        for (int s = 0; s < 2; ++s) {
            dst[10 * s + 0] = m[s];
            dst[10 * s + 1] = l[s];
#pragma unroll
            for (int j = 0; j < 4; ++j) {
                dst[10 * s + 2 + j] = ore[s][j];
                dst[10 * s + 6 + j] = oim[s][j];
            }
        }
    }
    __syncthreads();
    if (kh == 0) {
        const float* src = MB + (qpair * 64 + lane) * 20;
#pragma unroll
        for (int s = 0; s < 2; ++s) {
            float mp = src[10 * s + 0], lp = src[10 * s + 1];
            float M  = fmaxf(m[s], mp);
            float sa = __expf(m[s] - M), sb = __expf(mp - M);
            l[s] = l[s] * sa + lp * sb;
#pragma unroll
            for (int j = 0; j < 4; ++j) {
                ore[s][j] = ore[s][j] * sa + src[10 * s + 2 + j] * sb;
                oim[s][j] = oim[s][j] * sa + src[10 * s + 6 + j] * sb;
            }
            // total l per q-row: sum the 4 g-group partials
            float lt = l[s];
            lt += __shfl_xor(lt, 16);
            lt += __shfl_xor(lt, 32);
            if (frow_s[s] < FDIM) {
                float inv = 1.f / lt;
#pragma unroll
                for (int j = 0; j < 4; ++j) {
                    int c = 4 * g + j;
                    if (c < CDIM)
                        outspec[((size_t)(bg * CDIM + c)) * FDIM + frow_s[s]] =
                            make_float2(ore[s][j] * inv, oim[s][j] * inv);
                }
            }
        }
    }
}

// ---------------- Kernel 4: two-for-one irfft(1024) ----------------
__global__ void fft_inv2(const float2* __restrict__ spec, float* __restrict__ out) {
    __shared__ float re[1024], im[1024];
    const int s2 = blockIdx.x;                   // pair 0..1039
    const float2* Y1 = spec + (size_t)(2 * s2) * FDIM;
    const float2* Y2 = Y1 + FDIM;
    for (int t = threadIdx.x; t < 1024; t += blockDim.x) {
        float a, b, c, d;
        if (t <= 512) {
            float2 y1 = Y1[t], y2 = Y2[t];
            bool edge = (t == 0) | (t == 512);
            a = y1.x; b = edge ? 0.f : y1.y;
            c = y2.x; d = edge ? 0.f : y2.y;
        } else {
            float2 y1 = Y1[1024 - t], y2 = Y2[1024 - t];
            a = y1.x; b = -y1.y;
            c = y2.x; d = -y2.y;
        }
        unsigned r = bitrev10(t);
        re[r] = a - d;
        im[r] = b + c;
    }
    __syncthreads();
    for (int s = 0; s < 10; ++s) {
        int half = 1 << s;
        for (int j = threadIdx.x; j < 512; j += blockDim.x) {
            int grp = j >> s;
            int pos = j & (half - 1);
            int i1 = (grp << (s + 1)) + pos;
            int i2 = i1 + half;
            float ang = (float)M_PI * (float)pos / (float)half;   // +sign = inverse
            float sw, cw; __sincosf(ang, &sw, &cw);
            float xr = re[i2], xi = im[i2];
            float tr = cw * xr - sw * xi;
            float ti = cw * xi + sw * xr;
            float ur = re[i1], ui = im[i1];
            re[i1] = ur + tr; im[i1] = ui + ti;
            re[i2] = ur - tr; im[i2] = ui - ti;
        }
        __syncthreads();
    }
    const float scale = 1.0f / 1024.0f;
    float* o1 = out + (size_t)(2 * s2) * TDIM;
    for (int t = threadIdx.x; t < 1024; t += blockDim.x) {
        o1[t]        = re[t] * scale;
        o1[TDIM + t] = im[t] * scale;
    }
}

extern "C" void kernel_launch(void* const* d_in, const int* in_sizes, int n_in,
                              void* d_out, int out_size, void* d_ws, size_t ws_size,
                              hipStream_t stream) {
    const float* x  = (const float*)d_in[0];
    const float* wq = (const float*)d_in[1];
    const float* wk = (const float*)d_in[2];
    const float* wv = (const float*)d_in[3];
    float* out = (float*)d_out;

    const size_t n = (size_t)NROW * CDIM;        // 1,067,040 complex per buffer
    float2* xf = (float2*)d_ws;                  // x_fft, later reused as out-spectrum
    float2* q  = xf + n;                         // 8.54 MB
    _Float16* KP = (_Float16*)(q + n);           // NROW*64 halves = 10.51 MB
    _Float16* VT = KP + (size_t)NROW * 64;       // BG*2*16*520 halves = 5.32 MB

    fft_fwd2<<<BG * CDIM / 2, 256, 0, stream>>>(x, xf);
    qkv_kernel<<<(NROW * CDIM + 255) / 256, 256, 0, stream>>>(xf, wq, wk, wv, q, KP, VT);
    attn_kernel<<<BG * NCHUNK, 256, 0, stream>>>(q, KP, VT, xf /* outspec, aliases xf */);
    fft_inv2<<<BG * CDIM / 2, 256, 0, stream>>>(xf, out);
}